// Round 12
// baseline (247.417 us; speedup 1.0000x reference)
//
#include <hip/hip_runtime.h>
#include <hip/hip_fp16.h>
#include <math.h>

constexpr int INDIM = 256;
constexpr int HID   = 128;
constexpr int HEADS = 4;
constexpr int HC    = HEADS * HID;   // 512

typedef __attribute__((ext_vector_type(8))) _Float16 f16x8;
typedef __attribute__((ext_vector_type(4))) float    f32x4;

#define GLOAD_LDS16(gsrc, ldst)                                                        \
  __builtin_amdgcn_global_load_lds((const __attribute__((address_space(1))) void*)(gsrc), \
                                   (__attribute__((address_space(3))) void*)(ldst), 16, 0, 0)

// ---------------- MFMA f16 GEMM, 128x64 tile, 4 waves (final projection) ----------------
__global__ __launch_bounds__(256) void gemm_f16_mfma(const __half* __restrict__ A,
                                                     const __half* __restrict__ BT,
                                                     float* __restrict__ Cf,
                                                     const float* __restrict__ bias,
                                                     int M, int N, int K) {
  __shared__ _Float16 Asm[128 * 32];
  __shared__ _Float16 Bsm[64 * 32];
  const int tid = threadIdx.x;
  const int w = tid >> 6, l = tid & 63;
  const int wr = w >> 1, wc = w & 1;
  const int row0 = blockIdx.y * 128, col0 = blockIdx.x * 64;

  const int src_kq   = (l & 3) ^ ((l >> 2) & 3) ^ ((l >> 4) & 3);
  const int read_off = (((l >> 4) ^ (l & 3) ^ ((l >> 2) & 3)) * 8);

  f32x4 acc[4][2] = {};

  for (int kt = 0; kt < K; kt += 32) {
#pragma unroll
    for (int c = 0; c < 2; ++c) {
      const int R0 = w * 32 + c * 16;
      int row = row0 + R0 + (l >> 2);
      if (row >= M) row = M - 1;
      GLOAD_LDS16(&A[(size_t)row * K + kt + src_kq * 8], &Asm[R0 * 32]);
    }
    {
      const int R0 = w * 16;
      const int row = col0 + R0 + (l >> 2);
      GLOAD_LDS16(&BT[(size_t)row * K + kt + src_kq * 8], &Bsm[R0 * 32]);
    }
    __syncthreads();

    f16x8 bfr[2];
#pragma unroll
    for (int nf = 0; nf < 2; ++nf) {
      const int nl = wc * 32 + nf * 16 + (l & 15);
      bfr[nf] = *(const f16x8*)&Bsm[nl * 32 + read_off];
    }
#pragma unroll
    for (int mf = 0; mf < 4; ++mf) {
      const int ml = wr * 64 + mf * 16 + (l & 15);
      const f16x8 afr = *(const f16x8*)&Asm[ml * 32 + read_off];
#pragma unroll
      for (int nf = 0; nf < 2; ++nf)
        acc[mf][nf] = __builtin_amdgcn_mfma_f32_16x16x32_f16(afr, bfr[nf], acc[mf][nf], 0, 0, 0);
    }
    __syncthreads();
  }

#pragma unroll
  for (int mf = 0; mf < 4; ++mf) {
#pragma unroll
    for (int r = 0; r < 4; ++r) {
      const int row = row0 + wr * 64 + mf * 16 + (l >> 4) * 4 + r;
      if (row < M) {
#pragma unroll
        for (int nf = 0; nf < 2; ++nf) {
          const int col = col0 + wc * 32 + nf * 16 + (l & 15);
          Cf[(size_t)row * N + col] = acc[mf][nf][r] + bias[col];
        }
      }
    }
  }
}

// ---------------- MFMA f16 GEMM, 128x128 tile, 8 waves (layer GEMMs) ----------------
// Output written HEAD-MAJOR: Ch[head][row][c], head = col block. Epilogue emits
// exact s_src/s_dst for that head.
__global__ __launch_bounds__(512) void gemm_f16_mfma_128(const __half* __restrict__ A,
                                                         const __half* __restrict__ BT,
                                                         __half* __restrict__ Ch,
                                                         const float* __restrict__ att_src,
                                                         const float* __restrict__ att_dst,
                                                         float* __restrict__ ssrc,
                                                         float* __restrict__ sdst,
                                                         int M, int N, int K) {
  __shared__ _Float16 Asm[128 * 32];
  __shared__ _Float16 Bsm[128 * 32];
  const int tid = threadIdx.x;
  const int w = tid >> 6, l = tid & 63;
  const int wr = w >> 2, wc = w & 3;
  const int row0 = blockIdx.y * 128, col0 = blockIdx.x * 128;

  const int src_kq   = (l & 3) ^ ((l >> 2) & 3) ^ ((l >> 4) & 3);
  const int read_off = (((l >> 4) ^ (l & 3) ^ ((l >> 2) & 3)) * 8);

  f32x4 acc[4][2] = {};

  for (int kt = 0; kt < K; kt += 32) {
    const int R0 = w * 16;
    int rowA = row0 + R0 + (l >> 2);
    if (rowA >= M) rowA = M - 1;
    GLOAD_LDS16(&A[(size_t)rowA * K + kt + src_kq * 8], &Asm[R0 * 32]);
    const int rowB = col0 + R0 + (l >> 2);
    GLOAD_LDS16(&BT[(size_t)rowB * K + kt + src_kq * 8], &Bsm[R0 * 32]);
    __syncthreads();

    f16x8 bfr[2];
#pragma unroll
    for (int nf = 0; nf < 2; ++nf) {
      const int nl = wc * 32 + nf * 16 + (l & 15);
      bfr[nf] = *(const f16x8*)&Bsm[nl * 32 + read_off];
    }
#pragma unroll
    for (int mf = 0; mf < 4; ++mf) {
      const int ml = wr * 64 + mf * 16 + (l & 15);
      const f16x8 afr = *(const f16x8*)&Asm[ml * 32 + read_off];
#pragma unroll
      for (int nf = 0; nf < 2; ++nf)
        acc[mf][nf] = __builtin_amdgcn_mfma_f32_16x16x32_f16(afr, bfr[nf], acc[mf][nf], 0, 0, 0);
    }
    __syncthreads();
  }

  const int head = col0 >> 7;
  __half* chb = Ch + (size_t)head * M * HID;
#pragma unroll
  for (int mf = 0; mf < 4; ++mf) {
#pragma unroll
    for (int r = 0; r < 4; ++r) {
      const int row = row0 + wr * 64 + mf * 16 + (l >> 4) * 4 + r;
      if (row < M) {
#pragma unroll
        for (int nf = 0; nf < 2; ++nf) {
          const int c = wc * 32 + nf * 16 + (l & 15);
          chb[(size_t)row * HID + c] = __float2half(acc[mf][nf][r]);
        }
      }
    }
  }

  if (att_src) {
    float asv[2], adv[2];
#pragma unroll
    for (int nf = 0; nf < 2; ++nf) {
      const int c = wc * 32 + nf * 16 + (l & 15);
      asv[nf] = att_src[head * HID + c];
      adv[nf] = att_dst[head * HID + c];
    }
    __shared__ float sred[2][128][4];
#pragma unroll
    for (int mf = 0; mf < 4; ++mf) {
#pragma unroll
      for (int r = 0; r < 4; ++r) {
        float ps = acc[mf][0][r] * asv[0] + acc[mf][1][r] * asv[1];
        float pd = acc[mf][0][r] * adv[0] + acc[mf][1][r] * adv[1];
#pragma unroll
        for (int mk = 1; mk < 16; mk <<= 1) {
          ps += __shfl_xor(ps, mk);
          pd += __shfl_xor(pd, mk);
        }
        if ((l & 15) == 0) {
          const int rl = wr * 64 + mf * 16 + (l >> 4) * 4 + r;
          sred[0][rl][wc] = ps;
          sred[1][rl][wc] = pd;
        }
      }
    }
    __syncthreads();
    if (tid < 128) {
      const int row = row0 + tid;
      if (row < M) {
        ssrc[row * HEADS + head] = sred[0][tid][0] + sred[0][tid][1] + sred[0][tid][2] + sred[0][tid][3];
        sdst[row * HEADS + head] = sred[1][tid][0] + sred[1][tid][1] + sred[1][tid][2] + sred[1][tid][3];
      }
    }
  }
}

// ---------------- fused prep: x->f16 + all weight transposes ----------------
__global__ void prep_fused(const float* __restrict__ x, __half* __restrict__ x16, int nx4,
                           const float* __restrict__ W1, __half* __restrict__ w1t,
                           const float* __restrict__ W2, __half* __restrict__ w2t,
                           const float* __restrict__ Wo, __half* __restrict__ wot) {
  int g = blockIdx.x * blockDim.x + threadIdx.x;
  if (g < nx4) {
    const int i = g * 4;
    float4 v = *(const float4*)&x[i];
    __half2 a = __float22half2_rn(make_float2(v.x, v.y));
    __half2 b = __float22half2_rn(make_float2(v.z, v.w));
    *(uint2*)&x16[i] = make_uint2(*(unsigned*)&a, *(unsigned*)&b);
    return;
  }
  g -= nx4;
  if (g < INDIM * HC) {
    const int n = g / INDIM, k = g % INDIM;
    w1t[g] = __float2half(W1[(size_t)k * HC + n]);
    return;
  }
  g -= INDIM * HC;
  if (g < HID * HC) {
    const int n = g / HID, k = g % HID;
    w2t[g] = __float2half(W2[(size_t)k * HC + n]);
    return;
  }
  g -= HID * HC;
  if (g < HID * HID) {
    const int n = g / HID, k = g % HID;
    wot[g] = __float2half(Wo[(size_t)k * HID + n]);
  }
}

// ---------------- CSR build: segments = dst*4 + src_quadrant ----------------
// Quadrant-ordered edge lists give temporal L2 locality in the gather (all
// waves sweep src-quadrant phases together; per-XCD working set ~1.28 MB).
__global__ void degree_kernel(const int* __restrict__ ei, int E, int N,
                              int* __restrict__ deg) {
  int e = blockIdx.x * blockDim.x + threadIdx.x;
  int total = E + N;
  if (e >= total) return;
  int src, dst;
  if (e < E) { src = ei[e]; dst = ei[E + e]; }
  else       { src = dst = e - E; }
  const int quad = src / (N >> 2);
  atomicAdd(&deg[dst * 4 + quad], 1);
}

// int4-vectorized single-block scan over NS entries (NS = 4N)
__global__ __launch_bounds__(1024) void scan_kernel(const int* __restrict__ deg,
                                                    int* __restrict__ rowstart,
                                                    int* __restrict__ cursor, int NS) {
  __shared__ int sums[1024];
  const int tid = threadIdx.x;
  const int per = ((NS + 1023) / 1024 + 3) & ~3;
  int begin = tid * per;
  int end = begin + per; if (end > NS) end = NS;
  if (begin > NS) begin = NS;
  int s = 0;
  for (int i = begin; i + 3 < end; i += 4) {
    int4 v = *(const int4*)&deg[i];
    s += v.x + v.y + v.z + v.w;
  }
  sums[tid] = s;
  __syncthreads();
  for (int off = 1; off < 1024; off <<= 1) {
    int v = (tid >= off) ? sums[tid - off] : 0;
    __syncthreads();
    sums[tid] += v;
    __syncthreads();
  }
  int run = (tid == 0) ? 0 : sums[tid - 1];
  for (int i = begin; i + 3 < end; i += 4) {
    int4 v = *(const int4*)&deg[i];
    int4 rr;
    rr.x = run;
    rr.y = run + v.x;
    rr.z = run + v.x + v.y;
    rr.w = run + v.x + v.y + v.z;
    *(int4*)&rowstart[i] = rr;
    *(int4*)&cursor[i]   = rr;
    run += v.x + v.y + v.z + v.w;
  }
  if (tid == 1023) rowstart[NS] = sums[1023];
}

// csr_boff: byte offset of src row in a per-head slice: src * HID * 2.
__global__ void scatter_kernel(const int* __restrict__ ei, int E, int N,
                               int* __restrict__ cursor,
                               int* __restrict__ csr_boff, int* __restrict__ csr_dst) {
  int e = blockIdx.x * blockDim.x + threadIdx.x;
  int total = E + N;
  if (e >= total) return;
  int src, dst;
  if (e < E) { src = ei[e]; dst = ei[E + e]; }
  else       { src = dst = e - E; }
  const int quad = src / (N >> 2);
  int pos = atomicAdd(&cursor[dst * 4 + quad], 1);
  csr_boff[pos] = src * (HID * 2);
  csr_dst[pos] = dst;
}

// ---------------- per-edge softmax weights, PLANAR [4][total] ----------------
__global__ void edge_weights(const int* __restrict__ csr_boff,
                             const int* __restrict__ csr_dst,
                             const float4* __restrict__ ssrc4,
                             const float4* __restrict__ sdst4,
                             float* __restrict__ wtab, int total) {
  const int j = blockIdx.x * blockDim.x + threadIdx.x;
  if (j >= total) return;
  const float4 s = ssrc4[csr_boff[j] >> 8];
  const float4 dq = sdst4[csr_dst[j]];
  float e0 = s.x + dq.x, e1 = s.y + dq.y, e2 = s.z + dq.z, e3 = s.w + dq.w;
  e0 = (e0 > 0.f) ? e0 : 0.2f * e0;
  e1 = (e1 > 0.f) ? e1 : 0.2f * e1;
  e2 = (e2 > 0.f) ? e2 : 0.2f * e2;
  e3 = (e3 > 0.f) ? e3 : 0.2f * e3;
  wtab[j]             = __expf(fminf(e0, 60.f));
  wtab[total + j]     = __expf(fminf(e1, 60.f));
  wtab[2 * total + j] = __expf(fminf(e2, 60.f));
  wtab[3 * total + j] = __expf(fminf(e3, 60.f));
}

// ---------------- head-partitioned aggregate (quadrant-ordered edges) ----------------
// One wave per (node, head); blockIdx%8 -> XCD, 2 XCDs per head. The node's
// whole edge range [rowstart[4n], rowstart[4n+4]) is walked in one pass; the
// quadrant ordering gives temporal L2 locality. Wave = 4 edge-groups x 16
// lanes, 16B/lane; dual chains -> 8 edges / 2KB in flight. Single
// normalization; writes normalized per-head partials.
__global__ __launch_bounds__(256) void gat_aggregate_h(const __half* __restrict__ h,
                                                       const float* __restrict__ wtab,
                                                       const int* __restrict__ rowstart,
                                                       const int* __restrict__ csr_boff,
                                                       __half* __restrict__ part,
                                                       int N, int total) {
  const int b = blockIdx.x;
  const int x = b & 7, g = b >> 3;
  const int head = x >> 1;
  const int wave = threadIdx.x >> 6;
  const int lane = threadIdx.x & 63;
  const int grp = lane >> 4;
  const int sub = lane & 15;
  const int n = (g * 2 + (x & 1)) * 4 + wave;
  if (n >= N) return;
  const int rs = rowstart[n * 4], re = rowstart[n * 4 + 4];
  const char* hb = (const char*)(h + (size_t)head * N * HID) + sub * 16;
  const float* wt = wtab + (size_t)head * total;

  float d = 0.f;
  float a[8] = {};
  for (int j = rs; j < re; j += 8) {
    const int jA = j + grp, jB = j + 4 + grp;
    const int eA = (jA < re) ? jA : rs;
    const int eB = (jB < re) ? jB : rs;
    const float wA = (jA < re) ? wt[jA] : 0.f;
    const float wB = (jB < re) ? wt[jB] : 0.f;
    const int oA = csr_boff[eA];
    const int oB = csr_boff[eB];
    const int4 rawA = *(const int4*)(hb + oA);
    const int4 rawB = *(const int4*)(hb + oB);
    const __half* phA = (const __half*)&rawA;
    const __half* phB = (const __half*)&rawB;
    d += wA + wB;
#pragma unroll
    for (int k = 0; k < 8; ++k) {
      a[k] = fmaf(wA, __half2float(phA[k]), a[k]);
      a[k] = fmaf(wB, __half2float(phB[k]), a[k]);
    }
  }

  // merge the 4 edge-groups
  d += __shfl_xor(d, 16);
  d += __shfl_xor(d, 32);
#pragma unroll
  for (int k = 0; k < 8; ++k) {
    a[k] += __shfl_xor(a[k], 16);
    a[k] += __shfl_xor(a[k], 32);
  }

  if (lane < 16) {
    const float inv = 1.f / (d + 1e-16f);
    __half hv[8];
#pragma unroll
    for (int k = 0; k < 8; ++k) hv[k] = __float2half(a[k] * inv);
    *(int4*)((char*)(part + (size_t)head * N * HID) + (size_t)n * (HID * 2) + sub * 16) = *(int4*)hv;
  }
}

// ---------------- finalize: head mean + bias + elu -> f16 node-major ----------------
__global__ __launch_bounds__(256) void finalize_mean(const __half* __restrict__ part,
                                                     const float* __restrict__ bias,
                                                     __half* __restrict__ out, int N) {
  const int t = blockIdx.x * blockDim.x + threadIdx.x;
  if (t >= N * 64) return;
  const int n = t >> 6, cp = t & 63;
  const size_t hs = (size_t)N * HID;
  const __half2* p = (const __half2*)(part + (size_t)n * HID + cp * 2);
  float2 f0 = __half22float2(p[0]);
  float2 f1 = __half22float2(*(const __half2*)((const __half*)p + hs));
  float2 f2 = __half22float2(*(const __half2*)((const __half*)p + 2 * hs));
  float2 f3 = __half22float2(*(const __half2*)((const __half*)p + 3 * hs));
  float v0 = 0.25f * (f0.x + f1.x + f2.x + f3.x) + bias[cp * 2];
  float v1 = 0.25f * (f0.y + f1.y + f2.y + f3.y) + bias[cp * 2 + 1];
  v0 = (v0 > 0.f) ? v0 : expm1f(v0);
  v1 = (v1 > 0.f) ? v1 : expm1f(v1);
  *(__half2*)&out[(size_t)n * HID + cp * 2] = __float22half2_rn(make_float2(v0, v1));
}

// ---------------- launch ----------------
extern "C" void kernel_launch(void* const* d_in, const int* in_sizes, int n_in,
                              void* d_out, int out_size, void* d_ws, size_t ws_size,
                              hipStream_t stream) {
  const float* x    = (const float*)d_in[0];
  const int*   ei   = (const int*)d_in[1];
  const float* W1   = (const float*)d_in[2];
  const float* as1  = (const float*)d_in[3];
  const float* ad1  = (const float*)d_in[4];
  const float* b1   = (const float*)d_in[5];
  const float* W2   = (const float*)d_in[6];
  const float* as2  = (const float*)d_in[7];
  const float* ad2  = (const float*)d_in[8];
  const float* b2   = (const float*)d_in[9];
  const float* Wout = (const float*)d_in[10];
  const float* bout = (const float*)d_in[11];
  float* out = (float*)d_out;

  const int N = in_sizes[0] / INDIM;   // 20000
  const int E = in_sizes[1] / 2;       // 320000
  const int total = E + N;

  char* p = (char*)d_ws;
  auto alloc = [&](size_t bytes) -> void* {
    void* r = (void*)p;
    p += (bytes + 255) & ~(size_t)255;
    return r;
  };
  __half* x16  = (__half*)alloc((size_t)N * INDIM * 2);
  __half* h16  = (__half*)alloc((size_t)N * HC * 2);        // head-major [4][N][128]
  __half* part = (__half*)alloc((size_t)N * HC * 2);        // head-major partials
  __half* t1h  = (__half*)alloc((size_t)N * HID * 2);
  __half* t2h  = (__half*)alloc((size_t)N * HID * 2);
  __half* w1t  = (__half*)alloc((size_t)INDIM * HC * 2);
  __half* w2t  = (__half*)alloc((size_t)HID * HC * 2);
  __half* wot  = (__half*)alloc((size_t)HID * HID * 2);
  float* ssrc  = (float*)alloc((size_t)N * HEADS * 4);
  float* sdst  = (float*)alloc((size_t)N * HEADS * 4);
  float* wtab  = (float*)alloc((size_t)HEADS * total * 4);  // planar [4][total]
  int* deg     = (int*)alloc((size_t)4 * N * 4);
  int* rowst   = (int*)alloc(((size_t)4 * N + 4) * 4);
  int* cursor  = (int*)alloc((size_t)4 * N * 4);
  int* csr_b   = (int*)alloc((size_t)total * 4);
  int* csr_d   = (int*)alloc((size_t)total * 4);

  const int nx4 = N * INDIM / 4;
  const int prep_total = nx4 + INDIM * HC + HID * HC + HID * HID;
  prep_fused<<<(prep_total + 255) / 256, 256, 0, stream>>>(x, x16, nx4, W1, w1t, W2, w2t, Wout, wot);

  hipMemsetAsync(deg, 0, (size_t)4 * N * 4, stream);
  degree_kernel<<<(total + 255) / 256, 256, 0, stream>>>(ei, E, N, deg);
  scan_kernel<<<1, 1024, 0, stream>>>(deg, rowst, cursor, 4 * N);
  scatter_kernel<<<(total + 255) / 256, 256, 0, stream>>>(ei, E, N, cursor, csr_b, csr_d);

  const int mblk = (N + 127) / 128;
  const int eblk = (total + 255) / 256;
  const int ablk = ((N + 7) / 8) * 8;
  const int fblk = (N * 64 + 255) / 256;

  // layer 1
  gemm_f16_mfma_128<<<dim3(HC / 128, mblk), 512, 0, stream>>>(x16, w1t, h16, as1, ad1, ssrc, sdst, N, HC, INDIM);
  edge_weights<<<eblk, 256, 0, stream>>>(csr_b, csr_d, (const float4*)ssrc, (const float4*)sdst, wtab, total);
  gat_aggregate_h<<<ablk, 256, 0, stream>>>(h16, wtab, rowst, csr_b, part, N, total);
  finalize_mean<<<fblk, 256, 0, stream>>>(part, b1, t1h, N);
  // layer 2
  gemm_f16_mfma_128<<<dim3(HC / 128, mblk), 512, 0, stream>>>(t1h, w2t, h16, as2, ad2, ssrc, sdst, N, HC, HID);
  edge_weights<<<eblk, 256, 0, stream>>>(csr_b, csr_d, (const float4*)ssrc, (const float4*)sdst, wtab, total);
  gat_aggregate_h<<<ablk, 256, 0, stream>>>(h16, wtab, rowst, csr_b, part, N, total);
  finalize_mean<<<fblk, 256, 0, stream>>>(part, b2, t2h, N);
  // output projection
  gemm_f16_mfma<<<dim3(HID / 64, mblk), 256, 0, stream>>>(t2h, wot, out, bout, N, HID, HID);
}

// Round 13
// 202.292 us; speedup vs baseline: 1.2231x; 1.2231x over previous
//
#include <hip/hip_runtime.h>
#include <hip/hip_fp16.h>
#include <math.h>

constexpr int INDIM = 256;
constexpr int HID   = 128;
constexpr int HEADS = 4;
constexpr int HC    = HEADS * HID;   // 512

typedef __attribute__((ext_vector_type(8))) _Float16 f16x8;
typedef __attribute__((ext_vector_type(4))) float    f32x4;

#define GLOAD_LDS16(gsrc, ldst)                                                        \
  __builtin_amdgcn_global_load_lds((const __attribute__((address_space(1))) void*)(gsrc), \
                                   (__attribute__((address_space(3))) void*)(ldst), 16, 0, 0)

// ---------------- MFMA f16 GEMM, 128x64 tile, 4 waves (final projection) ----------------
__global__ __launch_bounds__(256) void gemm_f16_mfma(const __half* __restrict__ A,
                                                     const __half* __restrict__ BT,
                                                     float* __restrict__ Cf,
                                                     const float* __restrict__ bias,
                                                     int M, int N, int K) {
  __shared__ _Float16 Asm[128 * 32];
  __shared__ _Float16 Bsm[64 * 32];
  const int tid = threadIdx.x;
  const int w = tid >> 6, l = tid & 63;
  const int wr = w >> 1, wc = w & 1;
  const int row0 = blockIdx.y * 128, col0 = blockIdx.x * 64;

  const int src_kq   = (l & 3) ^ ((l >> 2) & 3) ^ ((l >> 4) & 3);
  const int read_off = (((l >> 4) ^ (l & 3) ^ ((l >> 2) & 3)) * 8);

  f32x4 acc[4][2] = {};

  for (int kt = 0; kt < K; kt += 32) {
#pragma unroll
    for (int c = 0; c < 2; ++c) {
      const int R0 = w * 32 + c * 16;
      int row = row0 + R0 + (l >> 2);
      if (row >= M) row = M - 1;
      GLOAD_LDS16(&A[(size_t)row * K + kt + src_kq * 8], &Asm[R0 * 32]);
    }
    {
      const int R0 = w * 16;
      const int row = col0 + R0 + (l >> 2);
      GLOAD_LDS16(&BT[(size_t)row * K + kt + src_kq * 8], &Bsm[R0 * 32]);
    }
    __syncthreads();

    f16x8 bfr[2];
#pragma unroll
    for (int nf = 0; nf < 2; ++nf) {
      const int nl = wc * 32 + nf * 16 + (l & 15);
      bfr[nf] = *(const f16x8*)&Bsm[nl * 32 + read_off];
    }
#pragma unroll
    for (int mf = 0; mf < 4; ++mf) {
      const int ml = wr * 64 + mf * 16 + (l & 15);
      const f16x8 afr = *(const f16x8*)&Asm[ml * 32 + read_off];
#pragma unroll
      for (int nf = 0; nf < 2; ++nf)
        acc[mf][nf] = __builtin_amdgcn_mfma_f32_16x16x32_f16(afr, bfr[nf], acc[mf][nf], 0, 0, 0);
    }
    __syncthreads();
  }

#pragma unroll
  for (int mf = 0; mf < 4; ++mf) {
#pragma unroll
    for (int r = 0; r < 4; ++r) {
      const int row = row0 + wr * 64 + mf * 16 + (l >> 4) * 4 + r;
      if (row < M) {
#pragma unroll
        for (int nf = 0; nf < 2; ++nf) {
          const int col = col0 + wc * 32 + nf * 16 + (l & 15);
          Cf[(size_t)row * N + col] = acc[mf][nf][r] + bias[col];
        }
      }
    }
  }
}

// ---------------- MFMA f16 GEMM, 128x128 tile, 8 waves (layer GEMMs) ----------------
// Output written HEAD-MAJOR: Ch[head][row][c], head = col block. Epilogue emits
// exact s_src/s_dst for that head.
__global__ __launch_bounds__(512) void gemm_f16_mfma_128(const __half* __restrict__ A,
                                                         const __half* __restrict__ BT,
                                                         __half* __restrict__ Ch,
                                                         const float* __restrict__ att_src,
                                                         const float* __restrict__ att_dst,
                                                         float* __restrict__ ssrc,
                                                         float* __restrict__ sdst,
                                                         int M, int N, int K) {
  __shared__ _Float16 Asm[128 * 32];
  __shared__ _Float16 Bsm[128 * 32];
  const int tid = threadIdx.x;
  const int w = tid >> 6, l = tid & 63;
  const int wr = w >> 2, wc = w & 3;
  const int row0 = blockIdx.y * 128, col0 = blockIdx.x * 128;

  const int src_kq   = (l & 3) ^ ((l >> 2) & 3) ^ ((l >> 4) & 3);
  const int read_off = (((l >> 4) ^ (l & 3) ^ ((l >> 2) & 3)) * 8);

  f32x4 acc[4][2] = {};

  for (int kt = 0; kt < K; kt += 32) {
    const int R0 = w * 16;
    int rowA = row0 + R0 + (l >> 2);
    if (rowA >= M) rowA = M - 1;
    GLOAD_LDS16(&A[(size_t)rowA * K + kt + src_kq * 8], &Asm[R0 * 32]);
    const int rowB = col0 + R0 + (l >> 2);
    GLOAD_LDS16(&BT[(size_t)rowB * K + kt + src_kq * 8], &Bsm[R0 * 32]);
    __syncthreads();

    f16x8 bfr[2];
#pragma unroll
    for (int nf = 0; nf < 2; ++nf) {
      const int nl = wc * 32 + nf * 16 + (l & 15);
      bfr[nf] = *(const f16x8*)&Bsm[nl * 32 + read_off];
    }
#pragma unroll
    for (int mf = 0; mf < 4; ++mf) {
      const int ml = wr * 64 + mf * 16 + (l & 15);
      const f16x8 afr = *(const f16x8*)&Asm[ml * 32 + read_off];
#pragma unroll
      for (int nf = 0; nf < 2; ++nf)
        acc[mf][nf] = __builtin_amdgcn_mfma_f32_16x16x32_f16(afr, bfr[nf], acc[mf][nf], 0, 0, 0);
    }
    __syncthreads();
  }

  const int head = col0 >> 7;
  __half* chb = Ch + (size_t)head * M * HID;
#pragma unroll
  for (int mf = 0; mf < 4; ++mf) {
#pragma unroll
    for (int r = 0; r < 4; ++r) {
      const int row = row0 + wr * 64 + mf * 16 + (l >> 4) * 4 + r;
      if (row < M) {
#pragma unroll
        for (int nf = 0; nf < 2; ++nf) {
          const int c = wc * 32 + nf * 16 + (l & 15);
          chb[(size_t)row * HID + c] = __float2half(acc[mf][nf][r]);
        }
      }
    }
  }

  if (att_src) {
    float asv[2], adv[2];
#pragma unroll
    for (int nf = 0; nf < 2; ++nf) {
      const int c = wc * 32 + nf * 16 + (l & 15);
      asv[nf] = att_src[head * HID + c];
      adv[nf] = att_dst[head * HID + c];
    }
    __shared__ float sred[2][128][4];
#pragma unroll
    for (int mf = 0; mf < 4; ++mf) {
#pragma unroll
      for (int r = 0; r < 4; ++r) {
        float ps = acc[mf][0][r] * asv[0] + acc[mf][1][r] * asv[1];
        float pd = acc[mf][0][r] * adv[0] + acc[mf][1][r] * adv[1];
#pragma unroll
        for (int mk = 1; mk < 16; mk <<= 1) {
          ps += __shfl_xor(ps, mk);
          pd += __shfl_xor(pd, mk);
        }
        if ((l & 15) == 0) {
          const int rl = wr * 64 + mf * 16 + (l >> 4) * 4 + r;
          sred[0][rl][wc] = ps;
          sred[1][rl][wc] = pd;
        }
      }
    }
    __syncthreads();
    if (tid < 128) {
      const int row = row0 + tid;
      if (row < M) {
        ssrc[row * HEADS + head] = sred[0][tid][0] + sred[0][tid][1] + sred[0][tid][2] + sred[0][tid][3];
        sdst[row * HEADS + head] = sred[1][tid][0] + sred[1][tid][1] + sred[1][tid][2] + sred[1][tid][3];
      }
    }
  }
}

// ---------------- fused prep: x->f16 + all weight transposes ----------------
__global__ void prep_fused(const float* __restrict__ x, __half* __restrict__ x16, int nx4,
                           const float* __restrict__ W1, __half* __restrict__ w1t,
                           const float* __restrict__ W2, __half* __restrict__ w2t,
                           const float* __restrict__ Wo, __half* __restrict__ wot) {
  int g = blockIdx.x * blockDim.x + threadIdx.x;
  if (g < nx4) {
    const int i = g * 4;
    float4 v = *(const float4*)&x[i];
    __half2 a = __float22half2_rn(make_float2(v.x, v.y));
    __half2 b = __float22half2_rn(make_float2(v.z, v.w));
    *(uint2*)&x16[i] = make_uint2(*(unsigned*)&a, *(unsigned*)&b);
    return;
  }
  g -= nx4;
  if (g < INDIM * HC) {
    const int n = g / INDIM, k = g % INDIM;
    w1t[g] = __float2half(W1[(size_t)k * HC + n]);
    return;
  }
  g -= INDIM * HC;
  if (g < HID * HC) {
    const int n = g / HID, k = g % HID;
    w2t[g] = __float2half(W2[(size_t)k * HC + n]);
    return;
  }
  g -= HID * HC;
  if (g < HID * HID) {
    const int n = g / HID, k = g % HID;
    wot[g] = __float2half(Wo[(size_t)k * HID + n]);
  }
}

// ---------------- CSR build: segments = dst*4 + src_quadrant ----------------
__global__ void degree_kernel(const int* __restrict__ ei, int E, int N,
                              int* __restrict__ deg) {
  int e = blockIdx.x * blockDim.x + threadIdx.x;
  int total = E + N;
  if (e >= total) return;
  int src, dst;
  if (e < E) { src = ei[e]; dst = ei[E + e]; }
  else       { src = dst = e - E; }
  const int quad = src / (N >> 2);
  atomicAdd(&deg[dst * 4 + quad], 1);
}

// ---------------- hierarchical scan (3 passes; NS divisible by 4) ----------------
// pass 1: block sums (1024 ints per block)
__global__ __launch_bounds__(256) void scan_bsum(const int* __restrict__ deg,
                                                 int* __restrict__ bsum, int NS) {
  const int tid = threadIdx.x;
  const int base = blockIdx.x * 1024 + tid * 4;
  int s = 0;
  if (base < NS) {
    int4 v = *(const int4*)&deg[base];
    s = v.x + v.y + v.z + v.w;
  }
#pragma unroll
  for (int off = 32; off > 0; off >>= 1) s += __shfl_down(s, off);
  __shared__ int ws[4];
  if ((tid & 63) == 0) ws[tid >> 6] = s;
  __syncthreads();
  if (tid == 0) bsum[blockIdx.x] = ws[0] + ws[1] + ws[2] + ws[3];
}

// pass 2: exclusive scan of block sums (single block; nblocks <= 1024)
__global__ __launch_bounds__(1024) void scan_boff(int* __restrict__ bsum, int nblocks) {
  __shared__ int tmp[1024];
  const int tid = threadIdx.x;
  int v = (tid < nblocks) ? bsum[tid] : 0;
  tmp[tid] = v;
  __syncthreads();
  for (int off = 1; off < 1024; off <<= 1) {
    int t = (tid >= off) ? tmp[tid - off] : 0;
    __syncthreads();
    tmp[tid] += t;
    __syncthreads();
  }
  if (tid < nblocks) bsum[tid] = tmp[tid] - v;   // exclusive
}

// pass 3: per-block exclusive scan + block offset -> rowstart & cursor
__global__ __launch_bounds__(256) void scan_write(const int* __restrict__ deg,
                                                  const int* __restrict__ bsum,
                                                  int* __restrict__ rowstart,
                                                  int* __restrict__ cursor,
                                                  int NS, int totalEdges) {
  const int tid = threadIdx.x;
  const int lane = tid & 63;
  const int wv = tid >> 6;
  const int base = blockIdx.x * 1024 + tid * 4;
  int4 v = make_int4(0, 0, 0, 0);
  if (base < NS) v = *(const int4*)&deg[base];
  const int ts = v.x + v.y + v.z + v.w;
  // inclusive wave scan of per-thread sums
  int pre = ts;
#pragma unroll
  for (int off = 1; off < 64; off <<= 1) {
    int t = __shfl_up(pre, off);
    if (lane >= off) pre += t;
  }
  __shared__ int wsum[4];
  if (lane == 63) wsum[wv] = pre;
  __syncthreads();
  int woff = 0;
#pragma unroll
  for (int i = 0; i < 4; ++i)
    if (i < wv) woff += wsum[i];
  const int run = bsum[blockIdx.x] + woff + (pre - ts);   // exclusive prefix
  if (base < NS) {
    int4 rr;
    rr.x = run;
    rr.y = run + v.x;
    rr.z = rr.y + v.y;
    rr.w = rr.z + v.z;
    *(int4*)&rowstart[base] = rr;
    *(int4*)&cursor[base]   = rr;
  }
  if (blockIdx.x == 0 && tid == 0) rowstart[NS] = totalEdges;
}

// csr_boff: byte offset of src row in a per-head slice: src * HID * 2.
__global__ void scatter_kernel(const int* __restrict__ ei, int E, int N,
                               int* __restrict__ cursor,
                               int* __restrict__ csr_boff, int* __restrict__ csr_dst) {
  int e = blockIdx.x * blockDim.x + threadIdx.x;
  int total = E + N;
  if (e >= total) return;
  int src, dst;
  if (e < E) { src = ei[e]; dst = ei[E + e]; }
  else       { src = dst = e - E; }
  const int quad = src / (N >> 2);
  int pos = atomicAdd(&cursor[dst * 4 + quad], 1);
  csr_boff[pos] = src * (HID * 2);
  csr_dst[pos] = dst;
}

// ---------------- per-edge softmax weights, PLANAR [4][total] ----------------
__global__ void edge_weights(const int* __restrict__ csr_boff,
                             const int* __restrict__ csr_dst,
                             const float4* __restrict__ ssrc4,
                             const float4* __restrict__ sdst4,
                             float* __restrict__ wtab, int total) {
  const int j = blockIdx.x * blockDim.x + threadIdx.x;
  if (j >= total) return;
  const float4 s = ssrc4[csr_boff[j] >> 8];
  const float4 dq = sdst4[csr_dst[j]];
  float e0 = s.x + dq.x, e1 = s.y + dq.y, e2 = s.z + dq.z, e3 = s.w + dq.w;
  e0 = (e0 > 0.f) ? e0 : 0.2f * e0;
  e1 = (e1 > 0.f) ? e1 : 0.2f * e1;
  e2 = (e2 > 0.f) ? e2 : 0.2f * e2;
  e3 = (e3 > 0.f) ? e3 : 0.2f * e3;
  wtab[j]             = __expf(fminf(e0, 60.f));
  wtab[total + j]     = __expf(fminf(e1, 60.f));
  wtab[2 * total + j] = __expf(fminf(e2, 60.f));
  wtab[3 * total + j] = __expf(fminf(e3, 60.f));
}

// ---------------- head-partitioned aggregate (quadrant-ordered edges) ----------------
__global__ __launch_bounds__(256) void gat_aggregate_h(const __half* __restrict__ h,
                                                       const float* __restrict__ wtab,
                                                       const int* __restrict__ rowstart,
                                                       const int* __restrict__ csr_boff,
                                                       __half* __restrict__ part,
                                                       int N, int total) {
  const int b = blockIdx.x;
  const int x = b & 7, g = b >> 3;
  const int head = x >> 1;
  const int wave = threadIdx.x >> 6;
  const int lane = threadIdx.x & 63;
  const int grp = lane >> 4;
  const int sub = lane & 15;
  const int n = (g * 2 + (x & 1)) * 4 + wave;
  if (n >= N) return;
  const int rs = rowstart[n * 4], re = rowstart[n * 4 + 4];
  const char* hb = (const char*)(h + (size_t)head * N * HID) + sub * 16;
  const float* wt = wtab + (size_t)head * total;

  float d = 0.f;
  float a[8] = {};
  for (int j = rs; j < re; j += 8) {
    const int jA = j + grp, jB = j + 4 + grp;
    const int eA = (jA < re) ? jA : rs;
    const int eB = (jB < re) ? jB : rs;
    const float wA = (jA < re) ? wt[jA] : 0.f;
    const float wB = (jB < re) ? wt[jB] : 0.f;
    const int oA = csr_boff[eA];
    const int oB = csr_boff[eB];
    const int4 rawA = *(const int4*)(hb + oA);
    const int4 rawB = *(const int4*)(hb + oB);
    const __half* phA = (const __half*)&rawA;
    const __half* phB = (const __half*)&rawB;
    d += wA + wB;
#pragma unroll
    for (int k = 0; k < 8; ++k) {
      a[k] = fmaf(wA, __half2float(phA[k]), a[k]);
      a[k] = fmaf(wB, __half2float(phB[k]), a[k]);
    }
  }

  d += __shfl_xor(d, 16);
  d += __shfl_xor(d, 32);
#pragma unroll
  for (int k = 0; k < 8; ++k) {
    a[k] += __shfl_xor(a[k], 16);
    a[k] += __shfl_xor(a[k], 32);
  }

  if (lane < 16) {
    const float inv = 1.f / (d + 1e-16f);
    __half hv[8];
#pragma unroll
    for (int k = 0; k < 8; ++k) hv[k] = __float2half(a[k] * inv);
    *(int4*)((char*)(part + (size_t)head * N * HID) + (size_t)n * (HID * 2) + sub * 16) = *(int4*)hv;
  }
}

// ---------------- finalize: head mean + bias + elu -> f16 node-major ----------------
__global__ __launch_bounds__(256) void finalize_mean(const __half* __restrict__ part,
                                                     const float* __restrict__ bias,
                                                     __half* __restrict__ out, int N) {
  const int t = blockIdx.x * blockDim.x + threadIdx.x;
  if (t >= N * 64) return;
  const int n = t >> 6, cp = t & 63;
  const size_t hs = (size_t)N * HID;
  const __half2* p = (const __half2*)(part + (size_t)n * HID + cp * 2);
  float2 f0 = __half22float2(p[0]);
  float2 f1 = __half22float2(*(const __half2*)((const __half*)p + hs));
  float2 f2 = __half22float2(*(const __half2*)((const __half*)p + 2 * hs));
  float2 f3 = __half22float2(*(const __half2*)((const __half*)p + 3 * hs));
  float v0 = 0.25f * (f0.x + f1.x + f2.x + f3.x) + bias[cp * 2];
  float v1 = 0.25f * (f0.y + f1.y + f2.y + f3.y) + bias[cp * 2 + 1];
  v0 = (v0 > 0.f) ? v0 : expm1f(v0);
  v1 = (v1 > 0.f) ? v1 : expm1f(v1);
  *(__half2*)&out[(size_t)n * HID + cp * 2] = __float22half2_rn(make_float2(v0, v1));
}

// ---------------- launch ----------------
extern "C" void kernel_launch(void* const* d_in, const int* in_sizes, int n_in,
                              void* d_out, int out_size, void* d_ws, size_t ws_size,
                              hipStream_t stream) {
  const float* x    = (const float*)d_in[0];
  const int*   ei   = (const int*)d_in[1];
  const float* W1   = (const float*)d_in[2];
  const float* as1  = (const float*)d_in[3];
  const float* ad1  = (const float*)d_in[4];
  const float* b1   = (const float*)d_in[5];
  const float* W2   = (const float*)d_in[6];
  const float* as2  = (const float*)d_in[7];
  const float* ad2  = (const float*)d_in[8];
  const float* b2   = (const float*)d_in[9];
  const float* Wout = (const float*)d_in[10];
  const float* bout = (const float*)d_in[11];
  float* out = (float*)d_out;

  const int N = in_sizes[0] / INDIM;   // 20000
  const int E = in_sizes[1] / 2;       // 320000
  const int total = E + N;
  const int NS = 4 * N;

  char* p = (char*)d_ws;
  auto alloc = [&](size_t bytes) -> void* {
    void* r = (void*)p;
    p += (bytes + 255) & ~(size_t)255;
    return r;
  };
  __half* x16  = (__half*)alloc((size_t)N * INDIM * 2);
  __half* h16  = (__half*)alloc((size_t)N * HC * 2);        // head-major [4][N][128]
  __half* part = (__half*)alloc((size_t)N * HC * 2);        // head-major partials
  __half* t1h  = (__half*)alloc((size_t)N * HID * 2);
  __half* t2h  = (__half*)alloc((size_t)N * HID * 2);
  __half* w1t  = (__half*)alloc((size_t)INDIM * HC * 2);
  __half* w2t  = (__half*)alloc((size_t)HID * HC * 2);
  __half* wot  = (__half*)alloc((size_t)HID * HID * 2);
  float* ssrc  = (float*)alloc((size_t)N * HEADS * 4);
  float* sdst  = (float*)alloc((size_t)N * HEADS * 4);
  float* wtab  = (float*)alloc((size_t)HEADS * total * 4);  // planar [4][total]
  int* deg     = (int*)alloc((size_t)NS * 4);
  int* rowst   = (int*)alloc(((size_t)NS + 4) * 4);
  int* cursor  = (int*)alloc((size_t)NS * 4);
  int* bsum    = (int*)alloc(1024 * 4);
  int* csr_b   = (int*)alloc((size_t)total * 4);
  int* csr_d   = (int*)alloc((size_t)total * 4);

  const int nx4 = N * INDIM / 4;
  const int prep_total = nx4 + INDIM * HC + HID * HC + HID * HID;
  prep_fused<<<(prep_total + 255) / 256, 256, 0, stream>>>(x, x16, nx4, W1, w1t, W2, w2t, Wout, wot);

  hipMemsetAsync(deg, 0, (size_t)NS * 4, stream);
  degree_kernel<<<(total + 255) / 256, 256, 0, stream>>>(ei, E, N, deg);
  const int sblk = (NS + 1023) / 1024;     // 79 blocks
  scan_bsum<<<sblk, 256, 0, stream>>>(deg, bsum, NS);
  scan_boff<<<1, 1024, 0, stream>>>(bsum, sblk);
  scan_write<<<sblk, 256, 0, stream>>>(deg, bsum, rowst, cursor, NS, total);
  scatter_kernel<<<(total + 255) / 256, 256, 0, stream>>>(ei, E, N, cursor, csr_b, csr_d);

  const int mblk = (N + 127) / 128;
  const int eblk = (total + 255) / 256;
  const int ablk = ((N + 7) / 8) * 8;
  const int fblk = (N * 64 + 255) / 256;

  // layer 1
  gemm_f16_mfma_128<<<dim3(HC / 128, mblk), 512, 0, stream>>>(x16, w1t, h16, as1, ad1, ssrc, sdst, N, HC, INDIM);
  edge_weights<<<eblk, 256, 0, stream>>>(csr_b, csr_d, (const float4*)ssrc, (const float4*)sdst, wtab, total);
  gat_aggregate_h<<<ablk, 256, 0, stream>>>(h16, wtab, rowst, csr_b, part, N, total);
  finalize_mean<<<fblk, 256, 0, stream>>>(part, b1, t1h, N);
  // layer 2
  gemm_f16_mfma_128<<<dim3(HC / 128, mblk), 512, 0, stream>>>(t1h, w2t, h16, as2, ad2, ssrc, sdst, N, HC, HID);
  edge_weights<<<eblk, 256, 0, stream>>>(csr_b, csr_d, (const float4*)ssrc, (const float4*)sdst, wtab, total);
  gat_aggregate_h<<<ablk, 256, 0, stream>>>(h16, wtab, rowst, csr_b, part, N, total);
  finalize_mean<<<fblk, 256, 0, stream>>>(part, b2, t2h, N);
  // output projection
  gemm_f16_mfma<<<dim3(HID / 64, mblk), 256, 0, stream>>>(t2h, wot, out, bout, N, HID, HID);
}